// Round 1
// baseline (973.989 us; speedup 1.0000x reference)
//
#include <hip/hip_runtime.h>

#define BATCH 128
#define SEQ   256
#define DD    64

// ws layout (floats): [0..15] meta (int t_star at 0), then K^T table [SEQ][64][64]
// total ws need = (16 + SEQ*4096)*4 bytes ~= 4.2 MB
#define WS_K 16

#define FMA16(c, a, b)                                          \
  c[0][0]=fmaf(a.x,b.x,c[0][0]); c[0][1]=fmaf(a.x,b.y,c[0][1]); \
  c[0][2]=fmaf(a.x,b.z,c[0][2]); c[0][3]=fmaf(a.x,b.w,c[0][3]); \
  c[1][0]=fmaf(a.y,b.x,c[1][0]); c[1][1]=fmaf(a.y,b.y,c[1][1]); \
  c[1][2]=fmaf(a.y,b.z,c[1][2]); c[1][3]=fmaf(a.y,b.w,c[1][3]); \
  c[2][0]=fmaf(a.z,b.x,c[2][0]); c[2][1]=fmaf(a.z,b.y,c[2][1]); \
  c[2][2]=fmaf(a.z,b.z,c[2][2]); c[2][3]=fmaf(a.z,b.w,c[2][3]); \
  c[3][0]=fmaf(a.w,b.x,c[3][0]); c[3][1]=fmaf(a.w,b.y,c[3][1]); \
  c[3][2]=fmaf(a.w,b.z,c[3][2]); c[3][3]=fmaf(a.w,b.w,c[3][3]);

// C[i][j] = sum_d At[d*64+i] * Bm[d*64+j]  (At holds A transposed; both float4-readable)
__device__ __forceinline__ void mm64(const float* __restrict__ At,
                                     const float* __restrict__ Bm,
                                     float c[4][4], int i0, int j0) {
#pragma unroll
  for (int k = 0; k < 4; ++k) { c[k][0]=0.f; c[k][1]=0.f; c[k][2]=0.f; c[k][3]=0.f; }
#pragma unroll 8
  for (int d = 0; d < 64; ++d) {
    float4 a = *(const float4*)(At + d*64 + i0);
    float4 b = *(const float4*)(Bm + d*64 + j0);
    FMA16(c, a, b)
  }
}

// C = A @ (2I - E):  c[i][j] = sum_d At[d][i] * ((d==j?2:0) - E[d][j])
__device__ __forceinline__ void mm64_newton(const float* __restrict__ At,
                                            const float* __restrict__ Em,
                                            float c[4][4], int i0, int j0) {
#pragma unroll
  for (int k = 0; k < 4; ++k) { c[k][0]=0.f; c[k][1]=0.f; c[k][2]=0.f; c[k][3]=0.f; }
#pragma unroll 4
  for (int d = 0; d < 64; ++d) {
    float4 a = *(const float4*)(At + d*64 + i0);
    float4 e = *(const float4*)(Em + d*64 + j0);
    float4 b;
    b.x = ((d == j0 + 0) ? 2.f : 0.f) - e.x;
    b.y = ((d == j0 + 1) ? 2.f : 0.f) - e.y;
    b.z = ((d == j0 + 2) ? 2.f : 0.f) - e.z;
    b.w = ((d == j0 + 3) ? 2.f : 0.f) - e.w;
    FMA16(c, a, b)
  }
}

__device__ __forceinline__ float blockMax256(float v, float* red) {
#pragma unroll
  for (int off = 32; off > 0; off >>= 1) v = fmaxf(v, __shfl_xor(v, off));
  const int tid = threadIdx.x;
  if ((tid & 63) == 0) red[tid >> 6] = v;
  __syncthreads();
  float m = fmaxf(fmaxf(red[0], red[1]), fmaxf(red[2], red[3]));
  __syncthreads();
  return m;
}

// ---------------- Kernel 1: single-WG Riccati recursion (data-independent) -------------
// Writes: K^T[t] into ws (t <= t_star), posterior P[t] directly into covs batch-0 rows,
// t_star into ws meta. Early-exits when P converges (time-invariant system).
__global__ void __launch_bounds__(256, 1)
k1_riccati(const float* __restrict__ Fg, const float* __restrict__ Hg,
           const float* __restrict__ LQg, const float* __restrict__ LRg,
           float* __restrict__ ws, float* __restrict__ covs) {
  __shared__ __align__(16) float sm[9 * 4096 + 96];
  float* FT  = sm + 0 * 4096;  // F^T
  float* HT  = sm + 1 * 4096;  // H^T
  float* P   = sm + 2 * 4096;  // posterior (symmetric)
  float* Pp  = sm + 3 * 4096;  // P_pred (symmetric)
  float* T2  = sm + 4 * 4096;  // H @ Pp            (= (Pp H^T)^T)
  float* T2T = sm + 5 * 4096;  // Pp @ H^T ; later reused as E = S@X
  float* Sm  = sm + 6 * 4096;  // S (symmetric)
  float* XA  = sm + 7 * 4096;  // Newton ping
  float* XB  = sm + 8 * 4096;  // Newton pong / scratch (T1^T, W)
  float* red = sm + 9 * 4096;  // 96 floats reduce scratch

  const int tid = threadIdx.x;
  const int i0 = (tid >> 4) << 2;
  const int j0 = (tid & 15) << 2;

  // One-time: transposes, P = I. Stash LQ^T in XA, LR^T in XB.
  for (int k = tid; k < 4096; k += 256) {
    const int r = k >> 6, cix = k & 63;
    FT[k] = Fg[cix * 64 + r];
    HT[k] = Hg[cix * 64 + r];
    XA[k] = LQg[cix * 64 + r];
    XB[k] = LRg[cix * 64 + r];
    P[k]  = (r == cix) ? 1.f : 0.f;
  }
  __syncthreads();

  // Q = LQ LQ^T, R = LR LR^T -> per-thread register tiles (each thread only ever
  // needs its own 4x4 tile of Q and R, in the Pp / S epilogues).
  float qreg[4][4], rreg[4][4];
  {
    float c[4][4];
    mm64(XA, XA, c, i0, j0);
#pragma unroll
    for (int k = 0; k < 4; ++k)
#pragma unroll
      for (int n = 0; n < 4; ++n) qreg[k][n] = c[k][n];
    mm64(XB, XB, c, i0, j0);
#pragma unroll
    for (int k = 0; k < 4; ++k)
#pragma unroll
      for (int n = 0; n < 4; ++n) rreg[k][n] = c[k][n];
  }
  __syncthreads();

  float* xinv = XA;  // current S^-1 estimate (warm-started across steps)
  float* xscr = XB;  // scratch
  int tstar = SEQ - 1;

  for (int t = 0; t < SEQ; ++t) {
    float c[4][4];

    // T1^T = (F @ P)^T  -> xscr
    mm64(FT, P, c, i0, j0);
#pragma unroll
    for (int n = 0; n < 4; ++n) {
      float4 v = make_float4(c[0][n], c[1][n], c[2][n], c[3][n]);
      *(float4*)(xscr + (j0 + n) * 64 + i0) = v;
    }
    __syncthreads();

    // Pp = T1 @ F^T + Q   (symmetric)
    mm64(xscr, FT, c, i0, j0);
#pragma unroll
    for (int k = 0; k < 4; ++k) {
      float4 v = make_float4(c[k][0] + qreg[k][0], c[k][1] + qreg[k][1],
                             c[k][2] + qreg[k][2], c[k][3] + qreg[k][3]);
      *(float4*)(Pp + (i0 + k) * 64 + j0) = v;
    }
    __syncthreads();

    // T2T = Pp @ H^T ; also store transposed copy T2 = H @ Pp
    mm64(Pp, HT, c, i0, j0);
#pragma unroll
    for (int k = 0; k < 4; ++k) {
      float4 v = make_float4(c[k][0], c[k][1], c[k][2], c[k][3]);
      *(float4*)(T2T + (i0 + k) * 64 + j0) = v;
    }
#pragma unroll
    for (int n = 0; n < 4; ++n) {
      float4 v = make_float4(c[0][n], c[1][n], c[2][n], c[3][n]);
      *(float4*)(T2 + (j0 + n) * 64 + i0) = v;
    }
    __syncthreads();

    // S = H @ T2T + R   (symmetric)
    mm64(HT, T2T, c, i0, j0);
#pragma unroll
    for (int k = 0; k < 4; ++k) {
      float4 v = make_float4(c[k][0] + rreg[k][0], c[k][1] + rreg[k][1],
                             c[k][2] + rreg[k][2], c[k][3] + rreg[k][3]);
      *(float4*)(Sm + (i0 + k) * 64 + j0) = v;
    }
    __syncthreads();

    // Cold-start Newton at t=0: X0 = S / ||S||_1^2 (S symmetric SPD => converges)
    if (t == 0) {
      if (tid < 64) {
        float s = 0.f;
        for (int i = 0; i < 64; ++i) s += fabsf(Sm[i * 64 + tid]);
        red[16 + tid] = s;
      }
      __syncthreads();
      if (tid == 0) {
        float m = 0.f;
        for (int i = 0; i < 64; ++i) m = fmaxf(m, red[16 + i]);
        red[4] = 1.f / (m * m);
      }
      __syncthreads();
      const float isc = red[4];
#pragma unroll
      for (int k = 0; k < 4; ++k)
#pragma unroll
        for (int n = 0; n < 4; ++n)
          xinv[(i0 + k) * 64 + j0 + n] = Sm[(i0 + k) * 64 + j0 + n] * isc;
      __syncthreads();
    }

    // Newton-Schulz: X <- X(2I - S X); warm-started, residual-checked.
    const int cap = (t == 0) ? 50 : 12;
    for (int it = 0; it < cap; ++it) {
      mm64(Sm, xinv, c, i0, j0);  // E = S @ X
      float r = 0.f;
#pragma unroll
      for (int k = 0; k < 4; ++k) {
#pragma unroll
        for (int n = 0; n < 4; ++n) {
          const float dlt = ((i0 + k) == (j0 + n)) ? 1.f : 0.f;
          r = fmaxf(r, fabsf(c[k][n] - dlt));
        }
        float4 v = make_float4(c[k][0], c[k][1], c[k][2], c[k][3]);
        *(float4*)(T2T + (i0 + k) * 64 + j0) = v;  // E overlays T2T (dead)
      }
      const float rall = blockMax256(r, red);
      if (rall < 1e-5f) break;
      mm64_newton(xinv, T2T, c, i0, j0);
#pragma unroll
      for (int k = 0; k < 4; ++k) {
        float4 v = make_float4(c[k][0], c[k][1], c[k][2], c[k][3]);
        *(float4*)(xscr + (i0 + k) * 64 + j0) = v;
      }
      __syncthreads();
      { float* tp = xinv; xinv = xscr; xscr = tp; }
      if (rall * rall < 1e-5f) break;  // post-update residual ~ rall^2
    }
    __syncthreads();

    // K = Pp H^T S^-1 = T2T @ X : At = T2, Bm = xinv.
    // Store K^T to ws (x-recursion wants K[d][e] as rows of e) and K^T into xscr (= W).
    mm64(T2, xinv, c, i0, j0);
    {
      float* Kt = ws + WS_K + (size_t)t * 4096;
#pragma unroll
      for (int n = 0; n < 4; ++n) {
        float4 v = make_float4(c[0][n], c[1][n], c[2][n], c[3][n]);
        *(float4*)(Kt + (j0 + n) * 64 + i0) = v;
        *(float4*)(xscr + (j0 + n) * 64 + i0) = v;  // W = K^T (since (X@T2)^T = T2T@X = K)
      }
    }
    __syncthreads();

    // M = K @ T2 (symmetric); P_new = Pp - M  (== Joseph form for optimal K)
    mm64(T2, xscr, c, i0, j0);
    float dmax = 0.f;
#pragma unroll
    for (int k = 0; k < 4; ++k)
#pragma unroll
      for (int n = 0; n < 4; ++n) {
        const int idx = (i0 + k) * 64 + j0 + n;
        const float pn = Pp[idx] - c[k][n];
        dmax = fmaxf(dmax, fabsf(pn - P[idx]));
        c[k][n] = pn;
      }
    __syncthreads();
#pragma unroll
    for (int k = 0; k < 4; ++k) {
      float4 v = make_float4(c[k][0], c[k][1], c[k][2], c[k][3]);
      *(float4*)(P + (i0 + k) * 64 + j0) = v;
    }
    __syncthreads();
    // symmetrize: read transpose partners, barrier, write own
    float trv[4][4];
#pragma unroll
    for (int k = 0; k < 4; ++k)
#pragma unroll
      for (int n = 0; n < 4; ++n) trv[k][n] = P[(j0 + n) * 64 + (i0 + k)];
    __syncthreads();
    {
      float* Pt = covs + (size_t)t * 4096;  // batch-0 covs row doubles as P table
#pragma unroll
      for (int k = 0; k < 4; ++k) {
        float4 v;
        v.x = 0.5f * (P[(i0 + k) * 64 + j0 + 0] + trv[k][0]);
        v.y = 0.5f * (P[(i0 + k) * 64 + j0 + 1] + trv[k][1]);
        v.z = 0.5f * (P[(i0 + k) * 64 + j0 + 2] + trv[k][2]);
        v.w = 0.5f * (P[(i0 + k) * 64 + j0 + 3] + trv[k][3]);
        *(float4*)(P + (i0 + k) * 64 + j0) = v;
        *(float4*)(Pt + (i0 + k) * 64 + j0) = v;
      }
    }
    const float dall = blockMax256(dmax, red);
    if (dall < 1e-5f) { tstar = t; break; }  // converged: K_t, P_t constant hereafter
  }
  if (tid == 0) *((int*)ws) = tstar;
}

// ------------- Kernel 2 (fused): x-recursion (WG < BATCH) + covs broadcast -------------
__global__ void __launch_bounds__(256, 4)
k2_fused(const float* __restrict__ x0, const float* __restrict__ U,
         const float* __restrict__ Y, const float* __restrict__ Fg,
         const float* __restrict__ Bg, const float* __restrict__ Hg,
         const float* __restrict__ ws, float* __restrict__ preds,
         float* __restrict__ covs) {
  const int tid = threadIdx.x;
  const int wg = blockIdx.x;
  const int tstar = *((const int*)ws);

  if (wg < BATCH) {
    // ---- per-batch sequential state recursion ----
    __shared__ __align__(16) float Kl[4096];  // K^T staged: Kl[e*64 + d]
    __shared__ __align__(16) float xv[64], xp[64], inn[64], us[64], ys[64];
    const int e = tid >> 2, q = tid & 3;
    float4 Fr[4], Br[4], Hr[4];
    {
      const float4* fp = (const float4*)(Fg + e * 64 + q * 16);
      const float4* bp = (const float4*)(Bg + e * 64 + q * 16);
      const float4* hp = (const float4*)(Hg + e * 64 + q * 16);
#pragma unroll
      for (int m = 0; m < 4; ++m) { Fr[m] = fp[m]; Br[m] = bp[m]; Hr[m] = hp[m]; }
    }
    if (tid < 64) xv[tid] = x0[wg * 64 + tid];
    int staged = -1;
    const float* Kall = ws + WS_K;

    for (int t = 0; t < SEQ; ++t) {
      const int se = (t < tstar) ? t : tstar;
      if (tid < 64) us[tid] = U[((size_t)wg * SEQ + t) * 64 + tid];
      else if (tid < 128) ys[tid - 64] = Y[((size_t)wg * SEQ + t) * 64 + (tid - 64)];
      if (se != staged) {  // after convergence K stops changing -> no re-staging
        const float4* Ks = (const float4*)(Kall + (size_t)se * 4096);
        float4* K4 = (float4*)Kl;
#pragma unroll
        for (int r2 = 0; r2 < 4; ++r2) K4[r2 * 256 + tid] = Ks[r2 * 256 + tid];
        staged = se;
      }
      __syncthreads();

      // x_pred[e] = sum_d xv[d]*F[e][d] + u[d]*B[e][d]
      const float4* xv4 = (const float4*)xv;
      const float4* us4 = (const float4*)us;
      float v = 0.f;
#pragma unroll
      for (int m = 0; m < 4; ++m) {
        float4 a = xv4[q * 4 + m], f = Fr[m];
        v = fmaf(a.x, f.x, fmaf(a.y, f.y, fmaf(a.z, f.z, fmaf(a.w, f.w, v))));
        float4 u4 = us4[q * 4 + m], b = Br[m];
        v = fmaf(u4.x, b.x, fmaf(u4.y, b.y, fmaf(u4.z, b.z, fmaf(u4.w, b.w, v))));
      }
      v += __shfl_xor(v, 1); v += __shfl_xor(v, 2);
      if (q == 0) xp[e] = v;
      __syncthreads();

      // innov[e] = y[e] - sum_d xp[d]*H[e][d]
      const float4* xp4 = (const float4*)xp;
      v = 0.f;
#pragma unroll
      for (int m = 0; m < 4; ++m) {
        float4 a = xp4[q * 4 + m], h = Hr[m];
        v = fmaf(a.x, h.x, fmaf(a.y, h.y, fmaf(a.z, h.z, fmaf(a.w, h.w, v))));
      }
      v += __shfl_xor(v, 1); v += __shfl_xor(v, 2);
      if (q == 0) inn[e] = ys[e] - v;
      __syncthreads();

      // x_new[e] = xp[e] + sum_d inn[d]*K[d][e]  (K^T rows are contiguous)
      const float4* in4 = (const float4*)inn;
      const float4* kl4 = (const float4*)(Kl + e * 64);
      v = 0.f;
#pragma unroll
      for (int m = 0; m < 4; ++m) {
        float4 a = in4[q * 4 + m], kk = kl4[q * 4 + m];
        v = fmaf(a.x, kk.x, fmaf(a.y, kk.y, fmaf(a.z, kk.z, fmaf(a.w, kk.w, v))));
      }
      v += __shfl_xor(v, 1); v += __shfl_xor(v, 2);
      if (q == 0) xv[e] = xp[e] + v;
      __syncthreads();
      if (tid < 64) preds[((size_t)wg * SEQ + t) * 64 + tid] = xv[tid];
    }
  } else {
    // ---- covs broadcast: covs[b][s] = P[min(s, t_star)] (P table = covs batch 0) ----
    const int nb = gridDim.x - BATCH;
    for (int p = wg - BATCH; p < BATCH * SEQ; p += nb) {
      const int s = p & (SEQ - 1);
      const int se = (s < tstar) ? s : tstar;
      if (p < SEQ && p <= tstar) continue;  // batch-0 rows already written by k1
      const float4* src = (const float4*)(covs + (size_t)se * 4096);
      float4* dst = (float4*)(covs + (size_t)p * 4096);
#pragma unroll
      for (int r2 = 0; r2 < 4; ++r2) dst[r2 * 256 + tid] = src[r2 * 256 + tid];
    }
  }
}

extern "C" void kernel_launch(void* const* d_in, const int* in_sizes, int n_in,
                              void* d_out, int out_size, void* d_ws, size_t ws_size,
                              hipStream_t stream) {
  (void)in_sizes; (void)n_in; (void)out_size; (void)ws_size;
  const float* x0 = (const float*)d_in[0];
  const float* U  = (const float*)d_in[1];
  const float* Y  = (const float*)d_in[2];
  const float* F  = (const float*)d_in[3];
  const float* B  = (const float*)d_in[4];
  const float* H  = (const float*)d_in[5];
  const float* LQ = (const float*)d_in[6];
  const float* LR = (const float*)d_in[7];
  float* preds = (float*)d_out;
  float* covs  = preds + (size_t)BATCH * SEQ * DD;
  float* ws    = (float*)d_ws;  // needs 16 + 256*4096 floats (~4.2 MB)

  hipLaunchKernelGGL(k1_riccati, dim3(1), dim3(256), 0, stream, F, H, LQ, LR, ws, covs);
  hipLaunchKernelGGL(k2_fused, dim3(BATCH + 1920), dim3(256), 0, stream,
                     x0, U, Y, F, B, H, ws, preds, covs);
}

// Round 2
// 832.281 us; speedup vs baseline: 1.1703x; 1.1703x over previous
//
#include <hip/hip_runtime.h>

#define BATCH 128
#define SEQ   256
#define DD    64

// ws layout (floats):
//  [0] t_star (int), [1] chunked_ok flag (int)
//  WS_K : K^T table [SEQ][64][64] (rows 0..t_star written)
//  WS_A : A  = (I-K*H)F   row-major [64][64]
//  WS_BP: Bp = (I-K*H)B   row-major
//  WS_KS: K*              row-major
#define WS_K  16
#define WS_A  (16 + SEQ * 4096)
#define WS_BP (WS_A + 4096)
#define WS_KS (WS_BP + 4096)

#define FMA16(c, a, b)                                          \
  c[0][0]=fmaf(a.x,b.x,c[0][0]); c[0][1]=fmaf(a.x,b.y,c[0][1]); \
  c[0][2]=fmaf(a.x,b.z,c[0][2]); c[0][3]=fmaf(a.x,b.w,c[0][3]); \
  c[1][0]=fmaf(a.y,b.x,c[1][0]); c[1][1]=fmaf(a.y,b.y,c[1][1]); \
  c[1][2]=fmaf(a.y,b.z,c[1][2]); c[1][3]=fmaf(a.y,b.w,c[1][3]); \
  c[2][0]=fmaf(a.z,b.x,c[2][0]); c[2][1]=fmaf(a.z,b.y,c[2][1]); \
  c[2][2]=fmaf(a.z,b.z,c[2][2]); c[2][3]=fmaf(a.z,b.w,c[2][3]); \
  c[3][0]=fmaf(a.w,b.x,c[3][0]); c[3][1]=fmaf(a.w,b.y,c[3][1]); \
  c[3][2]=fmaf(a.w,b.z,c[3][2]); c[3][3]=fmaf(a.w,b.w,c[3][3]);

// C[i][j] = sum_d At[d*64+i] * Bm[d*64+j]  (At = A transposed in LDS)
__device__ __forceinline__ void mm64(const float* __restrict__ At,
                                     const float* __restrict__ Bm,
                                     float c[4][4], int i0, int j0) {
#pragma unroll
  for (int k = 0; k < 4; ++k) { c[k][0]=0.f; c[k][1]=0.f; c[k][2]=0.f; c[k][3]=0.f; }
#pragma unroll 8
  for (int d = 0; d < 64; ++d) {
    float4 a = *(const float4*)(At + d*64 + i0);
    float4 b = *(const float4*)(Bm + d*64 + j0);
    FMA16(c, a, b)
  }
}

// C = A @ (2I - E)
__device__ __forceinline__ void mm64_newton(const float* __restrict__ At,
                                            const float* __restrict__ Em,
                                            float c[4][4], int i0, int j0) {
#pragma unroll
  for (int k = 0; k < 4; ++k) { c[k][0]=0.f; c[k][1]=0.f; c[k][2]=0.f; c[k][3]=0.f; }
#pragma unroll 4
  for (int d = 0; d < 64; ++d) {
    float4 a = *(const float4*)(At + d*64 + i0);
    float4 e = *(const float4*)(Em + d*64 + j0);
    float4 b;
    b.x = ((d == j0 + 0) ? 2.f : 0.f) - e.x;
    b.y = ((d == j0 + 1) ? 2.f : 0.f) - e.y;
    b.z = ((d == j0 + 2) ? 2.f : 0.f) - e.z;
    b.w = ((d == j0 + 3) ? 2.f : 0.f) - e.w;
    FMA16(c, a, b)
  }
}

__device__ __forceinline__ float blockMax256(float v, float* red) {
#pragma unroll
  for (int off = 32; off > 0; off >>= 1) v = fmaxf(v, __shfl_xor(v, off));
  const int tid = threadIdx.x;
  if ((tid & 63) == 0) red[tid >> 6] = v;
  __syncthreads();
  float m = fmaxf(fmaxf(red[0], red[1]), fmaxf(red[2], red[3]));
  __syncthreads();
  return m;
}

__device__ __forceinline__ float dot4(float4 a, float4 b, float acc) {
  return fmaf(a.x, b.x, fmaf(a.y, b.y, fmaf(a.z, b.z, fmaf(a.w, b.w, acc))));
}

// ---------------- Kernel 1: single-WG Riccati recursion (data-independent) -------------
__global__ void __launch_bounds__(256, 1)
k1_riccati(const float* __restrict__ Fg, const float* __restrict__ Bg,
           const float* __restrict__ Hg, const float* __restrict__ LQg,
           const float* __restrict__ LRg, float* __restrict__ ws,
           float* __restrict__ covs) {
  __shared__ __align__(16) float sm[9 * 4096 + 96];
  float* FT  = sm + 0 * 4096;  // F^T
  float* HT  = sm + 1 * 4096;  // H^T
  float* P   = sm + 2 * 4096;  // posterior
  float* Pp  = sm + 3 * 4096;  // P_pred
  float* T2  = sm + 4 * 4096;  // H @ Pp
  float* T2T = sm + 5 * 4096;  // Pp @ H^T ; reused as E = S@X
  float* Sm  = sm + 6 * 4096;  // S
  float* XA  = sm + 7 * 4096;  // Newton ping
  float* XB  = sm + 8 * 4096;  // Newton pong / scratch
  float* red = sm + 9 * 4096;

  const int tid = threadIdx.x;
  const int i0 = (tid >> 4) << 2;
  const int j0 = (tid & 15) << 2;

  for (int k = tid; k < 4096; k += 256) {
    const int r = k >> 6, cix = k & 63;
    FT[k] = Fg[cix * 64 + r];
    HT[k] = Hg[cix * 64 + r];
    XA[k] = LQg[cix * 64 + r];
    XB[k] = LRg[cix * 64 + r];
    P[k]  = (r == cix) ? 1.f : 0.f;
  }
  __syncthreads();

  float qreg[4][4], rreg[4][4];
  {
    float c[4][4];
    mm64(XA, XA, c, i0, j0);
#pragma unroll
    for (int k = 0; k < 4; ++k)
#pragma unroll
      for (int n = 0; n < 4; ++n) qreg[k][n] = c[k][n];
    mm64(XB, XB, c, i0, j0);
#pragma unroll
    for (int k = 0; k < 4; ++k)
#pragma unroll
      for (int n = 0; n < 4; ++n) rreg[k][n] = c[k][n];
  }
  __syncthreads();

  float* xinv = XA;
  float* xscr = XB;
  int tstar = SEQ - 1;

  for (int t = 0; t < SEQ; ++t) {
    float c[4][4];

    // T1^T = (F @ P)^T  -> xscr
    mm64(FT, P, c, i0, j0);
#pragma unroll
    for (int n = 0; n < 4; ++n)
      *(float4*)(xscr + (j0 + n) * 64 + i0) =
          make_float4(c[0][n], c[1][n], c[2][n], c[3][n]);
    __syncthreads();

    // Pp = T1 @ F^T + Q
    mm64(xscr, FT, c, i0, j0);
#pragma unroll
    for (int k = 0; k < 4; ++k)
      *(float4*)(Pp + (i0 + k) * 64 + j0) =
          make_float4(c[k][0] + qreg[k][0], c[k][1] + qreg[k][1],
                      c[k][2] + qreg[k][2], c[k][3] + qreg[k][3]);
    __syncthreads();

    // T2T = Pp @ H^T ; T2 = its transpose (= H @ Pp)
    mm64(Pp, HT, c, i0, j0);
#pragma unroll
    for (int k = 0; k < 4; ++k)
      *(float4*)(T2T + (i0 + k) * 64 + j0) =
          make_float4(c[k][0], c[k][1], c[k][2], c[k][3]);
#pragma unroll
    for (int n = 0; n < 4; ++n)
      *(float4*)(T2 + (j0 + n) * 64 + i0) =
          make_float4(c[0][n], c[1][n], c[2][n], c[3][n]);
    __syncthreads();

    // S = H @ T2T + R
    mm64(HT, T2T, c, i0, j0);
#pragma unroll
    for (int k = 0; k < 4; ++k)
      *(float4*)(Sm + (i0 + k) * 64 + j0) =
          make_float4(c[k][0] + rreg[k][0], c[k][1] + rreg[k][1],
                      c[k][2] + rreg[k][2], c[k][3] + rreg[k][3]);
    __syncthreads();

    if (t == 0) {  // cold-start scale for Newton-Schulz
      if (tid < 64) {
        float s = 0.f;
        for (int i = 0; i < 64; ++i) s += fabsf(Sm[i * 64 + tid]);
        red[16 + tid] = s;
      }
      __syncthreads();
      if (tid == 0) {
        float m = 0.f;
        for (int i = 0; i < 64; ++i) m = fmaxf(m, red[16 + i]);
        red[4] = 1.f / (m * m);
      }
      __syncthreads();
      const float isc = red[4];
#pragma unroll
      for (int k = 0; k < 4; ++k)
#pragma unroll
        for (int n = 0; n < 4; ++n)
          xinv[(i0 + k) * 64 + j0 + n] = Sm[(i0 + k) * 64 + j0 + n] * isc;
      __syncthreads();
    }

    // Newton-Schulz, warm-started; r_{new} <= r^2 (quadratic) so post-estimate = r*r
    const int cap = (t == 0) ? 40 : 6;
    for (int it = 0; it < cap; ++it) {
      mm64(Sm, xinv, c, i0, j0);  // E = S @ X
      float r = 0.f;
#pragma unroll
      for (int k = 0; k < 4; ++k) {
#pragma unroll
        for (int n = 0; n < 4; ++n) {
          const float dlt = ((i0 + k) == (j0 + n)) ? 1.f : 0.f;
          r = fmaxf(r, fabsf(c[k][n] - dlt));
        }
        *(float4*)(T2T + (i0 + k) * 64 + j0) =
            make_float4(c[k][0], c[k][1], c[k][2], c[k][3]);
      }
      const float rall = blockMax256(r, red);
      if (rall < 3e-4f) break;
      mm64_newton(xinv, T2T, c, i0, j0);
#pragma unroll
      for (int k = 0; k < 4; ++k)
        *(float4*)(xscr + (i0 + k) * 64 + j0) =
            make_float4(c[k][0], c[k][1], c[k][2], c[k][3]);
      __syncthreads();
      { float* tp = xinv; xinv = xscr; xscr = tp; }
      if (rall * rall < 3e-4f) break;
    }
    __syncthreads();

    // K = T2T @ X ; store K^T to ws row t and into xscr
    mm64(T2, xinv, c, i0, j0);
    {
      float* Kt = ws + WS_K + (size_t)t * 4096;
#pragma unroll
      for (int n = 0; n < 4; ++n) {
        float4 v = make_float4(c[0][n], c[1][n], c[2][n], c[3][n]);
        *(float4*)(Kt + (j0 + n) * 64 + i0) = v;
        *(float4*)(xscr + (j0 + n) * 64 + i0) = v;
      }
    }
    __syncthreads();

    // P_new = Pp - K @ T2
    mm64(T2, xscr, c, i0, j0);
    float dmax = 0.f;
#pragma unroll
    for (int k = 0; k < 4; ++k)
#pragma unroll
      for (int n = 0; n < 4; ++n) {
        const int idx = (i0 + k) * 64 + j0 + n;
        const float pn = Pp[idx] - c[k][n];
        dmax = fmaxf(dmax, fabsf(pn - P[idx]));
        c[k][n] = pn;
      }
    __syncthreads();
#pragma unroll
    for (int k = 0; k < 4; ++k)
      *(float4*)(P + (i0 + k) * 64 + j0) =
          make_float4(c[k][0], c[k][1], c[k][2], c[k][3]);
    __syncthreads();
    float trv[4][4];
#pragma unroll
    for (int k = 0; k < 4; ++k)
#pragma unroll
      for (int n = 0; n < 4; ++n) trv[k][n] = P[(j0 + n) * 64 + (i0 + k)];
    __syncthreads();
    {
      float* Pt = covs + (size_t)t * 4096;  // batch-0 covs row = P table
#pragma unroll
      for (int k = 0; k < 4; ++k) {
        float4 v;
        v.x = 0.5f * (P[(i0 + k) * 64 + j0 + 0] + trv[k][0]);
        v.y = 0.5f * (P[(i0 + k) * 64 + j0 + 1] + trv[k][1]);
        v.z = 0.5f * (P[(i0 + k) * 64 + j0 + 2] + trv[k][2]);
        v.w = 0.5f * (P[(i0 + k) * 64 + j0 + 3] + trv[k][3]);
        *(float4*)(P + (i0 + k) * 64 + j0) = v;
        *(float4*)(Pt + (i0 + k) * 64 + j0) = v;
      }
    }
    const float dall = blockMax256(dmax, red);
    if (dall < 1e-4f) { tstar = t; break; }
  }

  // ---- epilogue: constant-gain precompute. xscr holds K*^T. ----
  // Stage plain H->Pp, F->Sm, B->T2; K* row-major to ws.
  __syncthreads();
  for (int k = tid; k < 4096; k += 256) {
    Pp[k] = Hg[k]; Sm[k] = Fg[k]; T2[k] = Bg[k];
    ws[WS_KS + k] = xscr[(k & 63) * 64 + (k >> 6)];
  }
  __syncthreads();
  {
    float c[4][4];
    // IKH = I - K@H ; store IKH^T -> T2T
    mm64(xscr, Pp, c, i0, j0);
#pragma unroll
    for (int n = 0; n < 4; ++n) {
      float4 v;
      v.x = (((i0 + 0) == (j0 + n)) ? 1.f : 0.f) - c[0][n];
      v.y = (((i0 + 1) == (j0 + n)) ? 1.f : 0.f) - c[1][n];
      v.z = (((i0 + 2) == (j0 + n)) ? 1.f : 0.f) - c[2][n];
      v.w = (((i0 + 3) == (j0 + n)) ? 1.f : 0.f) - c[3][n];
      *(float4*)(T2T + (j0 + n) * 64 + i0) = v;
    }
    __syncthreads();
    // A = IKH @ F -> ws, and A -> xinv (rows), A^T -> P
    mm64(T2T, Sm, c, i0, j0);
#pragma unroll
    for (int k = 0; k < 4; ++k) {
      float4 v = make_float4(c[k][0], c[k][1], c[k][2], c[k][3]);
      *(float4*)(ws + WS_A + (i0 + k) * 64 + j0) = v;
      *(float4*)(xinv + (i0 + k) * 64 + j0) = v;
    }
#pragma unroll
    for (int n = 0; n < 4; ++n)
      *(float4*)(P + (j0 + n) * 64 + i0) =
          make_float4(c[0][n], c[1][n], c[2][n], c[3][n]);
    __syncthreads();
    // Bp = IKH @ B -> ws
    mm64(T2T, T2, c, i0, j0);
#pragma unroll
    for (int k = 0; k < 4; ++k)
      *(float4*)(ws + WS_BP + (i0 + k) * 64 + j0) =
          make_float4(c[k][0], c[k][1], c[k][2], c[k][3]);
    __syncthreads();
    // A2 = A@A : (P=A^T, xinv=A) -> A2->Pp, A2^T->Sm
    mm64(P, xinv, c, i0, j0);
#pragma unroll
    for (int k = 0; k < 4; ++k)
      *(float4*)(Pp + (i0 + k) * 64 + j0) =
          make_float4(c[k][0], c[k][1], c[k][2], c[k][3]);
#pragma unroll
    for (int n = 0; n < 4; ++n)
      *(float4*)(Sm + (j0 + n) * 64 + i0) =
          make_float4(c[0][n], c[1][n], c[2][n], c[3][n]);
    __syncthreads();
    // A4 : -> xinv, A4^T -> P
    mm64(Sm, Pp, c, i0, j0);
#pragma unroll
    for (int k = 0; k < 4; ++k)
      *(float4*)(xinv + (i0 + k) * 64 + j0) =
          make_float4(c[k][0], c[k][1], c[k][2], c[k][3]);
#pragma unroll
    for (int n = 0; n < 4; ++n)
      *(float4*)(P + (j0 + n) * 64 + i0) =
          make_float4(c[0][n], c[1][n], c[2][n], c[3][n]);
    __syncthreads();
    // A8 : -> Pp, A8^T -> Sm
    mm64(P, xinv, c, i0, j0);
#pragma unroll
    for (int k = 0; k < 4; ++k)
      *(float4*)(Pp + (i0 + k) * 64 + j0) =
          make_float4(c[k][0], c[k][1], c[k][2], c[k][3]);
#pragma unroll
    for (int n = 0; n < 4; ++n)
      *(float4*)(Sm + (j0 + n) * 64 + i0) =
          make_float4(c[0][n], c[1][n], c[2][n], c[3][n]);
    __syncthreads();
    // A16 = A8@A8 ; gate on max|A16| (row-sum bound: 64*max)
    mm64(Sm, Pp, c, i0, j0);
    float am = 0.f;
#pragma unroll
    for (int k = 0; k < 4; ++k)
#pragma unroll
      for (int n = 0; n < 4; ++n) am = fmaxf(am, fabsf(c[k][n]));
    const float amax = blockMax256(am, red);
    if (tid == 0) {
      ((int*)ws)[0] = tstar;
      ((int*)ws)[1] = (tstar <= 16 && amax < 1e-5f) ? 1 : 0;
    }
  }
}

// ------------- Kernel 2: chunked x-recursion (wave-per-unit) + covs broadcast ----------
#define NXWG 1024   // 128 batches x 8 chunks of 32 steps
#define NBWG 2048   // 256 s-values x 8 batch-groups

__global__ void __launch_bounds__(64, 1)
k2_fused(const float* __restrict__ x0, const float* __restrict__ U,
         const float* __restrict__ Y, const float* __restrict__ Fg,
         const float* __restrict__ Bg, const float* __restrict__ Hg,
         const float* __restrict__ ws, float* __restrict__ preds,
         float* __restrict__ covs) {
  const int e = threadIdx.x;
  const int wg = blockIdx.x;
  const int tstar = ((const int*)ws)[0];
  const int flag  = ((const int*)ws)[1];

  if (wg < NXWG) {
    const int b = wg >> 3, c = wg & 7;
    __shared__ __align__(16) float xv[64], xp[64], inn[64], us[2][64], ys[2][64];

    if (c == 0) {
      // exact sequential path (time-varying K for t <= t*); covers all t if !flag
      const int t1 = flag ? 32 : SEQ;
      float4 Fr[16], Br[16], Hr[16], Kr[16];
      const float4* fp = (const float4*)(Fg + e * 64);
      const float4* bp = (const float4*)(Bg + e * 64);
      const float4* hp = (const float4*)(Hg + e * 64);
#pragma unroll
      for (int m = 0; m < 16; ++m) { Fr[m] = fp[m]; Br[m] = bp[m]; Hr[m] = hp[m]; }
      xv[e] = x0[b * 64 + e];
      int staged = -1;
      for (int t = 0; t < t1; ++t) {
        const int se = (t < tstar) ? t : tstar;
        if (se != staged) {
          const float4* kp = (const float4*)(ws + WS_K + (size_t)se * 4096 + e * 64);
#pragma unroll
          for (int m = 0; m < 16; ++m) Kr[m] = kp[m];
          staged = se;
        }
        us[0][e] = U[((size_t)b * SEQ + t) * 64 + e];
        ys[0][e] = Y[((size_t)b * SEQ + t) * 64 + e];
        __syncthreads();
        const float4* xv4 = (const float4*)xv;
        const float4* us4 = (const float4*)us[0];
        float v = 0.f;
#pragma unroll
        for (int m = 0; m < 16; ++m) {
          v = dot4(Fr[m], xv4[m], v);
          v = dot4(Br[m], us4[m], v);
        }
        xp[e] = v;
        __syncthreads();
        const float4* xp4 = (const float4*)xp;
        float w = 0.f;
#pragma unroll
        for (int m = 0; m < 16; ++m) w = dot4(Hr[m], xp4[m], w);
        inn[e] = ys[0][e] - w;
        __syncthreads();
        const float4* in4 = (const float4*)inn;
        float z = 0.f;
#pragma unroll
        for (int m = 0; m < 16; ++m) z = dot4(Kr[m], in4[m], z);
        v = v + z;
        xv[e] = v;
        preds[((size_t)b * SEQ + t) * 64 + e] = v;
        __syncthreads();
      }
    } else {
      if (!flag) return;  // fallback: chunk 0 handles everything
      // steady-state chunk: x_t = A x_{t-1} + Bp u_t + K* y_t, burn-in 16 from zero
      const int tb = 32 * c - 16, out0 = 32 * c, t1 = 32 * c + 32;
      float4 Ar[16], Pr[16], Sr[16];
      const float4* ap = (const float4*)(ws + WS_A + e * 64);
      const float4* pp = (const float4*)(ws + WS_BP + e * 64);
      const float4* sp = (const float4*)(ws + WS_KS + e * 64);
#pragma unroll
      for (int m = 0; m < 16; ++m) { Ar[m] = ap[m]; Pr[m] = pp[m]; Sr[m] = sp[m]; }
      xv[e] = 0.f;
      float gu = U[((size_t)b * SEQ + tb) * 64 + e];
      float gy = Y[((size_t)b * SEQ + tb) * 64 + e];
      int pb = 0;
      for (int t = tb; t < t1; ++t) {
        us[pb][e] = gu; ys[pb][e] = gy;
        __syncthreads();  // orders prev xv write + u/y staging vs reads below
        if (t + 1 < t1) {
          gu = U[((size_t)b * SEQ + (t + 1)) * 64 + e];
          gy = Y[((size_t)b * SEQ + (t + 1)) * 64 + e];
        }
        const float4* xv4 = (const float4*)xv;
        const float4* us4 = (const float4*)us[pb];
        const float4* ys4 = (const float4*)ys[pb];
        float v = 0.f;
#pragma unroll
        for (int m = 0; m < 16; ++m) {
          v = dot4(Ar[m], xv4[m], v);
          v = dot4(Pr[m], us4[m], v);
          v = dot4(Sr[m], ys4[m], v);
        }
        xv[e] = v;  // program-order after all LDS reads of this wave
        if (t >= out0) preds[((size_t)b * SEQ + t) * 64 + e] = v;
        pb ^= 1;
      }
    }
  } else {
    // covs broadcast: read row min(s,t*) once into regs, write 16 batches
    const int bid2 = wg - NXWG;
    const int s = bid2 >> 3, bg = bid2 & 7;
    const int se = (s < tstar) ? s : tstar;
    const float4* src = (const float4*)(covs + (size_t)se * 4096);
    float4 r[16];
#pragma unroll
    for (int j = 0; j < 16; ++j) r[j] = src[j * 64 + e];
    for (int b = bg; b < BATCH; b += 8) {
      if (b == 0 && s <= tstar) continue;  // written by k1
      float4* dst = (float4*)(covs + ((size_t)b * SEQ + s) * 4096);
#pragma unroll
      for (int j = 0; j < 16; ++j) dst[j * 64 + e] = r[j];
    }
  }
}

extern "C" void kernel_launch(void* const* d_in, const int* in_sizes, int n_in,
                              void* d_out, int out_size, void* d_ws, size_t ws_size,
                              hipStream_t stream) {
  (void)in_sizes; (void)n_in; (void)out_size; (void)ws_size;
  const float* x0 = (const float*)d_in[0];
  const float* U  = (const float*)d_in[1];
  const float* Y  = (const float*)d_in[2];
  const float* F  = (const float*)d_in[3];
  const float* B  = (const float*)d_in[4];
  const float* H  = (const float*)d_in[5];
  const float* LQ = (const float*)d_in[6];
  const float* LR = (const float*)d_in[7];
  float* preds = (float*)d_out;
  float* covs  = preds + (size_t)BATCH * SEQ * DD;
  float* ws    = (float*)d_ws;  // needs ~4.25 MB

  hipLaunchKernelGGL(k1_riccati, dim3(1), dim3(256), 0, stream,
                     F, B, H, LQ, LR, ws, covs);
  hipLaunchKernelGGL(k2_fused, dim3(NXWG + NBWG), dim3(64), 0, stream,
                     x0, U, Y, F, B, H, ws, preds, covs);
}

// Round 3
// 709.803 us; speedup vs baseline: 1.3722x; 1.1726x over previous
//
#include <hip/hip_runtime.h>

#define BATCH 128
#define SEQ   256

// ws layout (floats): [0] t_star, [1] chunked-ok flag
#define WS_K  16
#define WS_A  (16 + SEQ * 4096)
#define WS_BP (WS_A + 4096)
#define WS_KS (WS_BP + 4096)

typedef unsigned short u16;
typedef float  f32x4v __attribute__((ext_vector_type(4)));
typedef __bf16 bf16x8 __attribute__((ext_vector_type(8)));
typedef unsigned short u16x8 __attribute__((ext_vector_type(8)));

struct Acc { f32x4v t[2][2]; };

__device__ __forceinline__ u16 bf16hi(float x) {
  unsigned u = __float_as_uint(x);
  return (u16)((u + 0x7fffu + ((u >> 16) & 1u)) >> 16);
}
__device__ __forceinline__ float bf16f(u16 h) {
  return __uint_as_float(((unsigned)h) << 16);
}

// XOR-swizzled chunk address (u16 units): array row a (0..63), 8-elem chunk c (0..7).
// Balances LDS banks for both b128 frag reads and b128 emit writes.
__device__ __forceinline__ int swadr(int a, int c) {
  return a * 64 + ((c ^ (a & 7)) << 3);
}

__device__ __forceinline__ bf16x8 frag(const u16* M, int strip, int kb, int q, int ln) {
  return *(const bf16x8*)(M + swadr(strip * 16 + ln, kb * 4 + q));
}

// acc += A @ B over K=64 with 3-term split-bf16.  A-slot: R-form [m][k] (hi, lo at
// +4096).  B-slot: T-form [n][k] (i.e. B^T row-major; for symmetric B pass R-form).
__device__ __forceinline__ void mm(const u16* As, const u16* Bs, Acc& acc,
                                   int R, int Cb, int q, int ln) {
#pragma unroll
  for (int kb = 0; kb < 2; ++kb) {
    bf16x8 ah[2], al[2], bh[2], bl[2];
#pragma unroll
    for (int i = 0; i < 2; ++i) {
      ah[i] = frag(As,        2 * R  + i, kb, q, ln);
      al[i] = frag(As + 4096, 2 * R  + i, kb, q, ln);
      bh[i] = frag(Bs,        2 * Cb + i, kb, q, ln);
      bl[i] = frag(Bs + 4096, 2 * Cb + i, kb, q, ln);
    }
#pragma unroll
    for (int i = 0; i < 2; ++i)
#pragma unroll
      for (int j = 0; j < 2; ++j) {
        acc.t[i][j] = __builtin_amdgcn_mfma_f32_16x16x32_bf16(ah[i], bh[j], acc.t[i][j], 0, 0, 0);
        acc.t[i][j] = __builtin_amdgcn_mfma_f32_16x16x32_bf16(ah[i], bl[j], acc.t[i][j], 0, 0, 0);
        acc.t[i][j] = __builtin_amdgcn_mfma_f32_16x16x32_bf16(al[i], bh[j], acc.t[i][j], 0, 0, 0);
      }
  }
}

__device__ __forceinline__ Acc accZero() {
  Acc a;
#pragma unroll
  for (int i = 0; i < 2; ++i)
#pragma unroll
    for (int j = 0; j < 2; ++j) {
      f32x4v z; z.x = 0.f; z.y = 0.f; z.z = 0.f; z.w = 0.f;
      a.t[i][j] = z;
    }
  return a;
}

__device__ __forceinline__ void storeC(float* dst, const Acc& a, int R, int Cb, int q, int ln) {
#pragma unroll
  for (int i = 0; i < 2; ++i)
#pragma unroll
    for (int j = 0; j < 2; ++j)
#pragma unroll
      for (int k = 0; k < 4; ++k)
        dst[(32 * R + 16 * i + 4 * q + k) * 64 + 32 * Cb + 16 * j + ln] = a.t[i][j][k];
}

// split 16 values at (row, cols cb..cb+15) into hi/lo bf16; write R-form and/or T-form
__device__ __forceinline__ void emit16(const float* v, int row, int cb, u16* Rs, u16* Ts) {
  u16 h[16], lo[16];
#pragma unroll
  for (int e = 0; e < 16; ++e) {
    h[e] = bf16hi(v[e]);
    lo[e] = bf16hi(v[e] - bf16f(h[e]));
  }
  if (Rs) {
#pragma unroll
    for (int c = 0; c < 2; ++c) {
      u16x8 vh, vl;
#pragma unroll
      for (int e = 0; e < 8; ++e) { vh[e] = h[8 * c + e]; vl[e] = lo[8 * c + e]; }
      const int ad = swadr(row, (cb >> 3) + c);
      *(u16x8*)(Rs + ad) = vh;
      *(u16x8*)(Rs + 4096 + ad) = vl;
    }
  }
  if (Ts) {
    const int rc = row >> 3, rr = row & 7;
#pragma unroll
    for (int e = 0; e < 16; ++e) {
      const int a = cb + e;
      const int ad = a * 64 + ((rc ^ (a & 7)) << 3) + rr;
      Ts[ad] = h[e];
      Ts[4096 + ad] = lo[e];
    }
  }
}

// mode 0: v=src; 1: v=src*scale; 2: v=(diag?dval:0)-src
__device__ __forceinline__ void splitsrc(const float* src, u16* Rs, u16* Ts,
                                         int mode, float scale, float dval, int tid) {
  const int row = tid >> 2, cb = (tid & 3) << 4;
  float v[16];
#pragma unroll
  for (int m = 0; m < 4; ++m) {
    f32x4v x = *(const f32x4v*)(src + row * 64 + cb + 4 * m);
    v[4 * m] = x.x; v[4 * m + 1] = x.y; v[4 * m + 2] = x.z; v[4 * m + 3] = x.w;
  }
  if (mode == 1) {
#pragma unroll
    for (int e = 0; e < 16; ++e) v[e] *= scale;
  } else if (mode == 2) {
#pragma unroll
    for (int e = 0; e < 16; ++e) v[e] = (((cb + e) == row) ? dval : 0.f) - v[e];
  }
  emit16(v, row, cb, Rs, Ts);
}

__device__ __forceinline__ float redmax(float v, float* red, int tid) {
#pragma unroll
  for (int off = 32; off > 0; off >>= 1) v = fmaxf(v, __shfl_xor(v, off));
  if ((tid & 63) == 0) red[300 + (tid >> 6)] = v;
  __syncthreads();
  float m = fmaxf(fmaxf(red[300], red[301]), fmaxf(red[302], red[303]));
  __syncthreads();
  return m;
}

__device__ __forceinline__ float dot4(float4 a, float4 b, float acc) {
  return fmaf(a.x, b.x, fmaf(a.y, b.y, fmaf(a.z, b.z, fmaf(a.w, b.w, acc))));
}

// ---------------- Kernel 1: single-WG Riccati via split-bf16 MFMA -------------------
__global__ void __launch_bounds__(256, 1)
k1_riccati(const float* __restrict__ Fg, const float* __restrict__ Bg,
           const float* __restrict__ Hg, const float* __restrict__ LQg,
           const float* __restrict__ LRg, float* __restrict__ ws,
           float* __restrict__ covs) {
  __shared__ __align__(16) u16 smb[7 * 8192];
  __shared__ __align__(16) float Mf32[4096];
  __shared__ __align__(16) float Ppf32[4096];
  __shared__ __align__(16) float red[308];

  const int tid = threadIdx.x;
  const int l = tid & 63, w = tid >> 6, q = l >> 4, ln = l & 15;
  const int R = w >> 1, Cb = w & 1;
  u16* SF = smb;                 // F  R-form (static)
  u16* SH = smb + 8192;          // H  R-form (static)
  u16* SX = smb + 2 * 8192;      // X ~= S^-1 (warm-started)
  u16* S1 = smb + 3 * 8192;      // rotating
  u16* S2 = smb + 4 * 8192;
  u16* S3 = smb + 5 * 8192;
  u16* S4 = smb + 6 * 8192;

  // init: F,H splits; Q = LQ LQ^T, R = LR LR^T into per-thread C-layout regs; P0 = I
  splitsrc(Fg, SF, nullptr, 0, 0, 0, tid);
  splitsrc(Hg, SH, nullptr, 0, 0, 0, tid);
  splitsrc(LQg, S1, nullptr, 0, 0, 0, tid);
  __syncthreads();
  Acc qacc = accZero(); mm(S1, S1, qacc, R, Cb, q, ln);
  __syncthreads();
  splitsrc(LRg, S1, nullptr, 0, 0, 0, tid);
  __syncthreads();
  Acc racc = accZero(); mm(S1, S1, racc, R, Cb, q, ln);
  __syncthreads();
  {
    const int row = tid >> 2, cb = (tid & 3) << 4;
    float v[16];
#pragma unroll
    for (int e = 0; e < 16; ++e) v[e] = ((cb + e) == row) ? 1.f : 0.f;
    emit16(v, row, cb, S4, nullptr);   // P0 = I
  }
  __syncthreads();

  int tstar = SEQ - 1;
  for (int t = 0; t < SEQ; ++t) {
    // (1) W2 = F @ P  (t=0: P=I -> W2=F)
    const u16* Wsrc = SF;
    if (t > 0) {
      Acc a = accZero(); mm(SF, S4, a, R, Cb, q, ln);
      storeC(Mf32, a, R, Cb, q, ln);
      __syncthreads();
      splitsrc(Mf32, S1, nullptr, 0, 0, 0, tid);
      __syncthreads();
      Wsrc = S1;
    }
    // (2) Pp = W2 @ F^T + Q
    {
      Acc a = qacc; mm(Wsrc, SF, a, R, Cb, q, ln);
      storeC(Ppf32, a, R, Cb, q, ln);
      __syncthreads();
      splitsrc(Ppf32, S2, nullptr, 0, 0, 0, tid);
      __syncthreads();
    }
    // (3) V2 = H @ Pp ; R->S3, T->S4
    {
      Acc a = accZero(); mm(SH, S2, a, R, Cb, q, ln);
      storeC(Mf32, a, R, Cb, q, ln);
      __syncthreads();
      splitsrc(Mf32, S3, S4, 0, 0, 0, tid);
      __syncthreads();
    }
    // (4) S = V2 @ H^T + R ; R->S2 (+ t0 X init: X0 = S/||S||_1^2)
    {
      Acc a = racc; mm(S3, SH, a, R, Cb, q, ln);
      storeC(Mf32, a, R, Cb, q, ln);
      __syncthreads();
      if (t == 0) {
        const int col = tid & 63, grp = tid >> 6;
        float s = 0.f;
        for (int r2 = grp * 16; r2 < grp * 16 + 16; ++r2) s += fabsf(Mf32[r2 * 64 + col]);
        red[tid] = s;
        __syncthreads();
        if (tid < 64) {
          float cs = red[tid] + red[64 + tid] + red[128 + tid] + red[192 + tid];
#pragma unroll
          for (int off = 32; off > 0; off >>= 1) cs = fmaxf(cs, __shfl_xor(cs, off));
          if (tid == 0) red[256] = 1.f / (cs * cs);
        }
        __syncthreads();
        const float sc = red[256];
        splitsrc(Mf32, SX, nullptr, 1, sc, 0, tid);
        __syncthreads();
      }
      splitsrc(Mf32, S2, nullptr, 0, 0, 0, tid);
      __syncthreads();
    }
    // (5) Newton-Schulz: X <- X (2I - S X), warm-started
    const int cap = (t == 0) ? 40 : 6;
    for (int it = 0; it < cap; ++it) {
      Acc e_ = accZero(); mm(S2, SX, e_, R, Cb, q, ln);
      float r = 0.f;
#pragma unroll
      for (int i = 0; i < 2; ++i)
#pragma unroll
        for (int j = 0; j < 2; ++j)
#pragma unroll
          for (int k = 0; k < 4; ++k) {
            const int gr = 32 * R + 16 * i + 4 * q + k;
            const int gc = 32 * Cb + 16 * j + ln;
            r = fmaxf(r, fabsf(e_.t[i][j][k] - ((gr == gc) ? 1.f : 0.f)));
          }
      const float rall = redmax(r, red, tid);
      if (rall < 5e-4f) break;
      storeC(Mf32, e_, R, Cb, q, ln);
      __syncthreads();
      splitsrc(Mf32, nullptr, S1, 2, 0, 2.0f, tid);  // T-form of (2I - E)
      __syncthreads();
      Acc x2 = accZero(); mm(SX, S1, x2, R, Cb, q, ln);
      storeC(Mf32, x2, R, Cb, q, ln);
      __syncthreads();
      splitsrc(Mf32, SX, nullptr, 0, 0, 0, tid);
      __syncthreads();
      if (rall * rall < 1e-4f) break;  // quadratic convergence estimate
    }
    // (6) KT = X @ V2 -> ws row t (K^T layout); K R-form -> S1; dK vs prev row
    float dk;
    {
      Acc a = accZero(); mm(SX, S4, a, R, Cb, q, ln);
      storeC(Mf32, a, R, Cb, q, ln);
      __syncthreads();
      const int row = tid >> 2, cb = (tid & 3) << 4;
      float v[16]; float dmax = (t == 0) ? 1e9f : 0.f;
      float* wrow = ws + WS_K + (size_t)t * 4096 + row * 64 + cb;
#pragma unroll
      for (int m = 0; m < 4; ++m) {
        f32x4v x = *(const f32x4v*)(Mf32 + row * 64 + cb + 4 * m);
        v[4 * m] = x.x; v[4 * m + 1] = x.y; v[4 * m + 2] = x.z; v[4 * m + 3] = x.w;
        *(f32x4v*)(wrow + 4 * m) = x;
      }
      if (t > 0) {
        const float* prow = wrow - 4096;
#pragma unroll
        for (int m = 0; m < 4; ++m) {
          f32x4v p = *(const f32x4v*)(prow + 4 * m);
          dmax = fmaxf(dmax, fmaxf(fmaxf(fabsf(v[4 * m] - p.x), fabsf(v[4 * m + 1] - p.y)),
                                   fmaxf(fabsf(v[4 * m + 2] - p.z), fabsf(v[4 * m + 3] - p.w))));
        }
      }
      emit16(v, row, cb, nullptr, S1);   // T-emit of K^T == K row-major
      dk = redmax(dmax, red, tid);       // barrier inside
    }
    // (7) M = K @ V2 ; Pn = Pp - sym(M) -> covs row t ; split R->S4 (P for next step)
    {
      Acc a = accZero(); mm(S1, S4, a, R, Cb, q, ln);
      storeC(Mf32, a, R, Cb, q, ln);
      __syncthreads();
      const int row = tid >> 2, cb = (tid & 3) << 4;
      float pv[16];
#pragma unroll
      for (int m = 0; m < 4; ++m) {
        f32x4v mij = *(const f32x4v*)(Mf32 + row * 64 + cb + 4 * m);
        f32x4v pp  = *(const f32x4v*)(Ppf32 + row * 64 + cb + 4 * m);
        pv[4 * m]     = pp.x - 0.5f * (mij.x + Mf32[(cb + 4 * m + 0) * 64 + row]);
        pv[4 * m + 1] = pp.y - 0.5f * (mij.y + Mf32[(cb + 4 * m + 1) * 64 + row]);
        pv[4 * m + 2] = pp.z - 0.5f * (mij.z + Mf32[(cb + 4 * m + 2) * 64 + row]);
        pv[4 * m + 3] = pp.w - 0.5f * (mij.w + Mf32[(cb + 4 * m + 3) * 64 + row]);
      }
      float* crow = covs + (size_t)t * 4096 + row * 64 + cb;
#pragma unroll
      for (int m = 0; m < 4; ++m) {
        f32x4v o; o.x = pv[4 * m]; o.y = pv[4 * m + 1]; o.z = pv[4 * m + 2]; o.w = pv[4 * m + 3];
        *(f32x4v*)(crow + 4 * m) = o;
      }
      emit16(pv, row, cb, S4, nullptr);
      __syncthreads();
    }
    if (dk < 1e-3f) { tstar = t; break; }
  }

  // ---- epilogue: IKH = I-K*H, A = IKH F, Bp = IKH B, K*, A^16 gate ----
  {
    Acc a = accZero(); mm(S1, SH, a, R, Cb, q, ln);   // K @ H
    storeC(Mf32, a, R, Cb, q, ln);
    __syncthreads();
    splitsrc(Mf32, S2, nullptr, 2, 0, 1.0f, tid);     // R-form of (I - KH)
    __syncthreads();
  }
  splitsrc(Fg, nullptr, S3, 0, 0, 0, tid);            // F T-form
  __syncthreads();
  {
    Acc a = accZero(); mm(S2, S3, a, R, Cb, q, ln);   // A = IKH @ F
    storeC(Mf32, a, R, Cb, q, ln);
#pragma unroll
    for (int i = 0; i < 2; ++i)
#pragma unroll
      for (int j = 0; j < 2; ++j)
#pragma unroll
        for (int k = 0; k < 4; ++k)
          ws[WS_A + (size_t)((32 * R + 16 * i + 4 * q + k) * 64 + 32 * Cb + 16 * j + ln)] = a.t[i][j][k];
    __syncthreads();
    splitsrc(Mf32, S1, S4, 0, 0, 0, tid);             // A: R->S1, T->S4
    __syncthreads();
  }
  splitsrc(Bg, nullptr, S3, 0, 0, 0, tid);            // B T-form
  __syncthreads();
  {
    Acc a = accZero(); mm(S2, S3, a, R, Cb, q, ln);   // Bp = IKH @ B
#pragma unroll
    for (int i = 0; i < 2; ++i)
#pragma unroll
      for (int j = 0; j < 2; ++j)
#pragma unroll
        for (int k = 0; k < 4; ++k)
          ws[WS_BP + (size_t)((32 * R + 16 * i + 4 * q + k) * 64 + 32 * Cb + 16 * j + ln)] = a.t[i][j][k];
  }
  {  // K* (K^T layout) = ws K-row tstar
    const int row = tid >> 2, cb = (tid & 3) << 4;
    const float* srcr = ws + WS_K + (size_t)tstar * 4096 + row * 64 + cb;
    float* dstr = ws + WS_KS + row * 64 + cb;
#pragma unroll
    for (int m = 0; m < 4; ++m) *(f32x4v*)(dstr + 4 * m) = *(const f32x4v*)(srcr + 4 * m);
  }
  __syncthreads();
  {  // A2
    Acc a = accZero(); mm(S1, S4, a, R, Cb, q, ln);
    storeC(Mf32, a, R, Cb, q, ln); __syncthreads();
    splitsrc(Mf32, S2, S3, 0, 0, 0, tid); __syncthreads();
  }
  {  // A4
    Acc a = accZero(); mm(S2, S3, a, R, Cb, q, ln);
    storeC(Mf32, a, R, Cb, q, ln); __syncthreads();
    splitsrc(Mf32, S1, S4, 0, 0, 0, tid); __syncthreads();
  }
  {  // A8
    Acc a = accZero(); mm(S1, S4, a, R, Cb, q, ln);
    storeC(Mf32, a, R, Cb, q, ln); __syncthreads();
    splitsrc(Mf32, S2, S3, 0, 0, 0, tid); __syncthreads();
  }
  {  // A16 gate
    Acc a = accZero(); mm(S2, S3, a, R, Cb, q, ln);
    float am = 0.f;
#pragma unroll
    for (int i = 0; i < 2; ++i)
#pragma unroll
      for (int j = 0; j < 2; ++j)
#pragma unroll
        for (int k = 0; k < 4; ++k) am = fmaxf(am, fabsf(a.t[i][j][k]));
    const float amax = redmax(am, red, tid);
    if (tid == 0) {
      ((int*)ws)[0] = tstar;
      ((int*)ws)[1] = (tstar <= 16 && amax < 1e-5f) ? 1 : 0;
    }
  }
}

// ------------- Kernel 2: covs broadcast (first) + chunked x-recursion ----------
#define NXWG 1024   // 128 batches x 8 chunks of 32 steps
#define NBWG 2048   // 256 s-values x 8 batch-groups

__global__ void __launch_bounds__(64, 1)
k2_fused(const float* __restrict__ x0, const float* __restrict__ U,
         const float* __restrict__ Y, const float* __restrict__ Fg,
         const float* __restrict__ Bg, const float* __restrict__ Hg,
         const float* __restrict__ ws, float* __restrict__ preds,
         float* __restrict__ covs) {
  const int e = threadIdx.x;
  const int wg = blockIdx.x;
  const int tstar = ((const int*)ws)[0];
  const int flag  = ((const int*)ws)[1];

  if (wg < NBWG) {
    // covs broadcast: read row min(s,t*) once into regs, write 16 batches
    const int s = wg >> 3, bg = wg & 7;
    const int se = (s < tstar) ? s : tstar;
    const float4* src = (const float4*)(covs + (size_t)se * 4096);
    float4 r[16];
#pragma unroll
    for (int j = 0; j < 16; ++j) r[j] = src[j * 64 + e];
    for (int b = bg; b < BATCH; b += 8) {
      if (b == 0 && s <= tstar) continue;  // written by k1
      float4* dst = (float4*)(covs + ((size_t)b * SEQ + s) * 4096);
#pragma unroll
      for (int j = 0; j < 16; ++j) dst[j * 64 + e] = r[j];
    }
  } else {
    const int xw = wg - NBWG;
    const int b = xw >> 3, c = xw & 7;
    __shared__ __align__(16) float xv[64], xp[64], inn[64], us[2][64], ys[2][64];

    if (c == 0) {
      // exact sequential path (time-varying K for t <= t*); covers all t if !flag
      const int t1 = flag ? 32 : SEQ;
      float4 Fr[16], Br[16], Hr[16], Kr[16];
      const float4* fp = (const float4*)(Fg + e * 64);
      const float4* bp = (const float4*)(Bg + e * 64);
      const float4* hp = (const float4*)(Hg + e * 64);
#pragma unroll
      for (int m = 0; m < 16; ++m) { Fr[m] = fp[m]; Br[m] = bp[m]; Hr[m] = hp[m]; }
      xv[e] = x0[b * 64 + e];
      int staged = -1;
      for (int t = 0; t < t1; ++t) {
        const int se = (t < tstar) ? t : tstar;
        if (se != staged) {
          const float4* kp = (const float4*)(ws + WS_K + (size_t)se * 4096 + e * 64);
#pragma unroll
          for (int m = 0; m < 16; ++m) Kr[m] = kp[m];
          staged = se;
        }
        us[0][e] = U[((size_t)b * SEQ + t) * 64 + e];
        ys[0][e] = Y[((size_t)b * SEQ + t) * 64 + e];
        __syncthreads();
        const float4* xv4 = (const float4*)xv;
        const float4* us4 = (const float4*)us[0];
        float v = 0.f;
#pragma unroll
        for (int m = 0; m < 16; ++m) {
          v = dot4(Fr[m], xv4[m], v);
          v = dot4(Br[m], us4[m], v);
        }
        xp[e] = v;
        __syncthreads();
        const float4* xp4 = (const float4*)xp;
        float w = 0.f;
#pragma unroll
        for (int m = 0; m < 16; ++m) w = dot4(Hr[m], xp4[m], w);
        inn[e] = ys[0][e] - w;
        __syncthreads();
        const float4* in4 = (const float4*)inn;
        float z = 0.f;
#pragma unroll
        for (int m = 0; m < 16; ++m) z = dot4(Kr[m], in4[m], z);
        v = v + z;
        xv[e] = v;
        preds[((size_t)b * SEQ + t) * 64 + e] = v;
        __syncthreads();
      }
    } else {
      if (!flag) return;  // fallback: chunk 0 handles everything
      // steady-state chunk: x_t = A x_{t-1} + Bp u_t + K* y_t, burn-in 16 from zero
      const int tb = 32 * c - 16, out0 = 32 * c, t1 = 32 * c + 32;
      float4 Ar[16], Pr[16], Sr[16];
      const float4* ap = (const float4*)(ws + WS_A + e * 64);
      const float4* pp = (const float4*)(ws + WS_BP + e * 64);
      const float4* sp = (const float4*)(ws + WS_KS + e * 64);
#pragma unroll
      for (int m = 0; m < 16; ++m) { Ar[m] = ap[m]; Pr[m] = pp[m]; Sr[m] = sp[m]; }
      xv[e] = 0.f;
      float gu = U[((size_t)b * SEQ + tb) * 64 + e];
      float gy = Y[((size_t)b * SEQ + tb) * 64 + e];
      int pb = 0;
      for (int t = tb; t < t1; ++t) {
        us[pb][e] = gu; ys[pb][e] = gy;
        __syncthreads();
        if (t + 1 < t1) {
          gu = U[((size_t)b * SEQ + (t + 1)) * 64 + e];
          gy = Y[((size_t)b * SEQ + (t + 1)) * 64 + e];
        }
        const float4* xv4 = (const float4*)xv;
        const float4* us4 = (const float4*)us[pb];
        const float4* ys4 = (const float4*)ys[pb];
        float v = 0.f;
#pragma unroll
        for (int m = 0; m < 16; ++m) {
          v = dot4(Ar[m], xv4[m], v);
          v = dot4(Pr[m], us4[m], v);
          v = dot4(Sr[m], ys4[m], v);
        }
        xv[e] = v;
        if (t >= out0) preds[((size_t)b * SEQ + t) * 64 + e] = v;
        pb ^= 1;
      }
    }
  }
}

extern "C" void kernel_launch(void* const* d_in, const int* in_sizes, int n_in,
                              void* d_out, int out_size, void* d_ws, size_t ws_size,
                              hipStream_t stream) {
  (void)in_sizes; (void)n_in; (void)out_size; (void)ws_size;
  const float* x0 = (const float*)d_in[0];
  const float* U  = (const float*)d_in[1];
  const float* Y  = (const float*)d_in[2];
  const float* F  = (const float*)d_in[3];
  const float* B  = (const float*)d_in[4];
  const float* H  = (const float*)d_in[5];
  const float* LQ = (const float*)d_in[6];
  const float* LR = (const float*)d_in[7];
  float* preds = (float*)d_out;
  float* covs  = preds + (size_t)BATCH * SEQ * 64;
  float* ws    = (float*)d_ws;  // needs ~4.25 MB

  hipLaunchKernelGGL(k1_riccati, dim3(1), dim3(256), 0, stream,
                     F, B, H, LQ, LR, ws, covs);
  hipLaunchKernelGGL(k2_fused, dim3(NBWG + NXWG), dim3(64), 0, stream,
                     x0, U, Y, F, B, H, ws, preds, covs);
}